// Round 6
// baseline (250.572 us; speedup 1.0000x reference)
//
#include <hip/hip_runtime.h>
#include <hip/hip_bf16.h>

#define D_DIM 256
#define K_CODES 1024
#define HW 1024
#define N_VEC 32768
#define N_ELEM 8388608ull

typedef __attribute__((ext_vector_type(8))) short bf16x8;
typedef __attribute__((ext_vector_type(4))) float f32x4;

static __device__ __forceinline__ unsigned short f2bf(float x) {
    union { __hip_bfloat16 h; unsigned short u; } cvt;
    cvt.h = __float2bfloat16(x);
    return cvt.u;
}

static __device__ __forceinline__ float bf2f(unsigned short u) {
    union { float f; unsigned int i; } cvt;
    cvt.i = ((unsigned int)u) << 16;
    return cvt.f;
}

// ---------------------------------------------------------------------------
// Kernel A (fused prep): codebook -> bf16 B-fragment order + codebook norms
// + zero counts/lossacc. 128 blocks x 256.
// ---------------------------------------------------------------------------
__global__ __launch_bounds__(256) void prep_kernel(const float* __restrict__ cb,
                                                   unsigned short* __restrict__ cbb,
                                                   float* __restrict__ cnorm,
                                                   int* __restrict__ counts,
                                                   float* __restrict__ lossacc) {
    int slot = blockIdx.x * 256 + threadIdx.x;  // 0 .. 32767
    {
        int lane = slot & 63;
        int dchunk = (slot >> 6) & 7;
        int ktile = slot >> 9;
        int code = ktile * 16 + (lane & 15);
        int d0 = dchunk * 32 + (lane >> 4) * 8;
        const float4* src = (const float4*)(cb + (size_t)code * D_DIM + d0);
        float4 v0 = src[0], v1 = src[1];
        int4 o;
        o.x = f2bf(v0.x) | ((unsigned)f2bf(v0.y) << 16);
        o.y = f2bf(v0.z) | ((unsigned)f2bf(v0.w) << 16);
        o.z = f2bf(v1.x) | ((unsigned)f2bf(v1.y) << 16);
        o.w = f2bf(v1.z) | ((unsigned)f2bf(v1.w) << 16);
        *(int4*)(cbb + (size_t)slot * 8) = o;
    }
    if (slot < 8192) {
        if (slot < K_CODES) counts[slot] = 0;
        if (slot == K_CODES) lossacc[0] = 0.f;
        int k = slot >> 3;
        int part = slot & 7;
        const float4* row = (const float4*)(cb + (size_t)k * D_DIM + part * 32);
        float s = 0.f;
#pragma unroll
        for (int i = 0; i < 8; i++) {
            float4 v = row[i];
            s = fmaf(v.x, v.x, s);
            s = fmaf(v.y, v.y, s);
            s = fmaf(v.z, v.z, s);
            s = fmaf(v.w, v.w, s);
        }
        s += __shfl_xor(s, 1);
        s += __shfl_xor(s, 2);
        s += __shfl_xor(s, 4);
        if (part == 0) cnorm[k] = s;
    }
}

// ---------------------------------------------------------------------------
// Mega kernel: argmin (R5 K-loop, unchanged) + quantized output + loss +
// (optionally) one-hot encodings — one block owns 128 n end-to-end.
// out = q exactly (ref's z+(q-z) == q within 1 ulp); loss uses bf16 z held in
// A-fragments (error ~1e-3, threshold 19.44). Codebook rows for the epilogue
// staged per-wave in LDS (stride 260 f32 => conflict-light b128 reads).
// ---------------------------------------------------------------------------
__global__ __launch_bounds__(256, 1) void mega_kernel(
    const float* __restrict__ z, const unsigned short* __restrict__ cbb,
    const float* __restrict__ cb, const float* __restrict__ cnorm,
    int* __restrict__ indices, int* __restrict__ counts,
    float* __restrict__ lossacc, float* __restrict__ quant,
    float* __restrict__ enc, int do_enc) {
    __shared__ __align__(16) char smraw[66560];  // K-loop dbuf 64KB / qs 65KB
    __shared__ int skl[128];
    __shared__ float wsum[4];

    const int t = threadIdx.x;
    const int lane = t & 63;
    const int w = t >> 6;                    // wave 0..3
    const int nt0 = blockIdx.x * 8 + w * 2;  // wave owns ntiles nt0, nt0+1

    // ---- prologue: load + convert A fragments (2 ntiles x 8 dchunks) ----
    bf16x8 Ar[2][8];
    {
        const int row = lane & 15;
        const int dq = (lane >> 4) * 8;
#pragma unroll
        for (int nt = 0; nt < 2; nt++) {
            int n = (nt0 + nt) * 16 + row;
            int b = n >> 10;
            int hw = n & (HW - 1);
#pragma unroll
            for (int dc = 0; dc < 8; dc++) {
                const float* src = z + (((size_t)(b * D_DIM + dc * 32 + dq)) << 10) + hw;
                union { bf16x8 v; unsigned short u[8]; } pk;
#pragma unroll
                for (int j = 0; j < 8; j++) pk.u[j] = f2bf(src[(size_t)j << 10]);
                Ar[nt][dc] = pk.v;
            }
        }
    }

    // ---- async stage of chunk 0 ----
    {
        const unsigned int* g = (const unsigned int*)cbb;
        unsigned int* l = (unsigned int*)smraw;
#pragma unroll
        for (int p = 0; p < 8; p++) {
            int off = (p * 256 + t) * 4;
            __builtin_amdgcn_global_load_lds(
                (const __attribute__((address_space(1))) unsigned int*)(g + off),
                (__attribute__((address_space(3))) unsigned int*)(l + off), 16, 0, 0);
        }
    }

    float bestd[2][4];
    int bestk[2][4];
#pragma unroll
    for (int nt = 0; nt < 2; nt++)
#pragma unroll
        for (int r = 0; r < 4; r++) { bestd[nt][r] = 3.4e38f; bestk[nt][r] = 0; }

    const int col = lane & 15;
    for (int c = 0; c < 16; c++) {
        const int cur = c & 1;
        __syncthreads();  // drains vmcnt -> current buf ready
        if (c < 15) {
            const unsigned int* g = (const unsigned int*)(cbb + (size_t)(c + 1) * 16384);
            unsigned int* l = (unsigned int*)(smraw + (size_t)(cur ^ 1) * 32768);
#pragma unroll
            for (int p = 0; p < 8; p++) {
                int off = (p * 256 + t) * 4;
                __builtin_amdgcn_global_load_lds(
                    (const __attribute__((address_space(1))) unsigned int*)(g + off),
                    (__attribute__((address_space(3))) unsigned int*)(l + off), 16, 0, 0);
            }
        }
        const unsigned short* Bb = (const unsigned short*)(smraw + (size_t)cur * 32768);
#pragma unroll
        for (int half = 0; half < 2; half++) {
            bf16x8 bb[2][8];
#pragma unroll
            for (int kt2 = 0; kt2 < 2; kt2++)
#pragma unroll
                for (int dc = 0; dc < 8; dc++)
                    bb[kt2][dc] = *(const bf16x8*)
                        &Bb[(((half * 2 + kt2) * 8 + dc) * 64 + lane) * 8];
            f32x4 acc[2][2];
#pragma unroll
            for (int nt = 0; nt < 2; nt++)
#pragma unroll
                for (int kt2 = 0; kt2 < 2; kt2++)
                    acc[nt][kt2] = (f32x4){0.f, 0.f, 0.f, 0.f};
#pragma unroll
            for (int dc = 0; dc < 8; dc++)
#pragma unroll
                for (int nt = 0; nt < 2; nt++)
#pragma unroll
                    for (int kt2 = 0; kt2 < 2; kt2++)
                        acc[nt][kt2] = __builtin_amdgcn_mfma_f32_16x16x32_bf16(
                            Ar[nt][dc], bb[kt2][dc], acc[nt][kt2], 0, 0, 0);
#pragma unroll
            for (int kt2 = 0; kt2 < 2; kt2++) {
                int k = (c * 4 + half * 2 + kt2) * 16 + col;
                float cn = cnorm[k];
#pragma unroll
                for (int nt = 0; nt < 2; nt++)
#pragma unroll
                    for (int r = 0; r < 4; r++) {
                        float sc = fmaf(-2.0f, acc[nt][kt2][r], cn);
                        if (sc < bestd[nt][r]) { bestd[nt][r] = sc; bestk[nt][r] = k; }
                    }
            }
        }
    }

    // ---- reduce across 16 columns -> per-n winner; publish to LDS + global ----
#pragma unroll
    for (int nt = 0; nt < 2; nt++)
#pragma unroll
        for (int r = 0; r < 4; r++) {
            float dd = bestd[nt][r];
            int kk = bestk[nt][r];
#pragma unroll
            for (int off = 8; off >= 1; off >>= 1) {
                float d2 = __shfl_xor(dd, off);
                int k2 = __shfl_xor(kk, off);
                if (d2 < dd || (d2 == dd && k2 < kk)) { dd = d2; kk = k2; }
            }
            if ((lane & 15) == 0) {
                int nloc = (w * 2 + nt) * 16 + (lane >> 4) * 4 + r;
                skl[nloc] = kk;
                indices[blockIdx.x * 128 + nloc] = kk;
                atomicAdd(&counts[kk], 1);
            }
        }
    __syncthreads();  // all waves done with K-loop LDS + skl complete

    // ---- epilogue: stage q rows per wave, write out = q, loss from bf16 z ----
    float* qsw = (float*)smraw + w * 4160;  // 16 rows x 260 f32 per wave
    float lsum = 0.f;
#pragma unroll
    for (int nt = 0; nt < 2; nt++) {
        {  // stage 16 rows (4 lanes per row, 64 f32 each) — wave-private region
            int r = lane & 15;
            int cseg = lane >> 4;
            int code = skl[(w * 2 + nt) * 16 + r];
            const float4* src = (const float4*)(cb + (size_t)code * D_DIM + cseg * 64);
            float* dst = qsw + r * 260 + cseg * 64;
#pragma unroll
            for (int q4 = 0; q4 < 16; q4++) *(float4*)(dst + q4 * 4) = src[q4];
        }
        // wave-internal lgkmcnt ordering suffices (region is wave-private)
        int n_row = (nt0 + nt) * 16 + (lane & 15);
        int b = n_row >> 10;
        int hw = n_row & (HW - 1);
        const int h = lane >> 4;
        const float* qrow = qsw + (lane & 15) * 260;
#pragma unroll
        for (int dc = 0; dc < 8; dc++) {
            int d0 = dc * 32 + h * 8;
            float4 q0 = *(const float4*)(qrow + d0);
            float4 q1 = *(const float4*)(qrow + d0 + 4);
            union { bf16x8 v; unsigned short u[8]; } pk;
            pk.v = Ar[nt][dc];
            float qv[8] = {q0.x, q0.y, q0.z, q0.w, q1.x, q1.y, q1.z, q1.w};
            float* outp = quant + (((size_t)(b * D_DIM + d0)) << 10) + hw;
#pragma unroll
            for (int j = 0; j < 8; j++) {
                outp[(size_t)j << 10] = qv[j];
                float e = qv[j] - bf2f(pk.u[j]);
                lsum = fmaf(e, e, lsum);
            }
        }
    }
#pragma unroll
    for (int off = 32; off >= 1; off >>= 1) lsum += __shfl_down(lsum, off);
    if (lane == 0) wsum[w] = lsum;
    __syncthreads();
    if (t == 0) atomicAdd(lossacc, wsum[0] + wsum[1] + wsum[2] + wsum[3]);

    // ---- one-hot encodings for this block's 128 n (coalesced, mostly zeros) ----
    if (do_enc) {
        const int base_n = blockIdx.x * 128;
        const int k0 = t << 2;  // thread's 4-column slice
#pragma unroll 4
        for (int i = 0; i < 128; i++) {
            int idx = skl[i];  // uniform per iteration
            float2 a, b2;
            a.x = (k0 == idx) ? 1.f : 0.f;
            a.y = (k0 + 1 == idx) ? 1.f : 0.f;
            b2.x = (k0 + 2 == idx) ? 1.f : 0.f;
            b2.y = (k0 + 3 == idx) ? 1.f : 0.f;
            float* p = enc + ((size_t)(base_n + i) << 10) + k0;
            *(float2*)p = a;
            *(float2*)(p + 2) = b2;
        }
    }
}

// ---------------------------------------------------------------------------
// Fallback: write one-hot encodings (used only when ws too small for cbb)
// ---------------------------------------------------------------------------
__global__ __launch_bounds__(256) void write_encodings(const int* __restrict__ indices,
                                                       float* __restrict__ enc) {
    int gid = blockIdx.x * 256 + threadIdx.x;
    int n = gid >> 8;
    int k0 = (gid & 255) << 2;
    int idx = indices[n];
    float2 a, b2;
    a.x = (k0 == idx) ? 1.f : 0.f;
    a.y = (k0 + 1 == idx) ? 1.f : 0.f;
    b2.x = (k0 + 2 == idx) ? 1.f : 0.f;
    b2.y = (k0 + 3 == idx) ? 1.f : 0.f;
    float* p = enc + (size_t)gid * 4;
    *(float2*)p = a;
    *(float2*)(p + 2) = b2;
}

// ---------------------------------------------------------------------------
// Finalize loss + perplexity
// ---------------------------------------------------------------------------
__global__ __launch_bounds__(256) void finalize_kernel(const int* __restrict__ counts,
                                                       const float* __restrict__ lossacc,
                                                       float* __restrict__ out_scalars) {
    int t = threadIdx.x;
    float s = 0.f;
#pragma unroll
    for (int i = 0; i < 4; i++) {
        int k = t + i * 256;
        float p = (float)counts[k] * (1.0f / 32768.0f);
        s += p * logf(p + 1e-10f);
    }
#pragma unroll
    for (int off = 32; off >= 1; off >>= 1) s += __shfl_down(s, off);
    __shared__ float red[4];
    if ((t & 63) == 0) red[t >> 6] = s;
    __syncthreads();
    if (t == 0) {
        float tot = red[0] + red[1] + red[2] + red[3];
        out_scalars[0] = 1.25f * (lossacc[0] * (1.0f / 8388608.0f));  // q + beta*e
        out_scalars[1] = expf(-tot);                                  // perplexity
    }
}

// ---------------------------------------------------------------------------
extern "C" void kernel_launch(void* const* d_in, const int* in_sizes, int n_in,
                              void* d_out, int out_size, void* d_ws, size_t ws_size,
                              hipStream_t stream) {
    const float* z = (const float*)d_in[0];   // [32,256,32,32]
    const float* cb = (const float*)d_in[1];  // [1024,256]
    float* out = (float*)d_out;
    char* wsb = (char*)d_ws;

    float* cnorm = (float*)wsb;             // 1024 f32
    int* counts = (int*)(wsb + 4096);       // 1024 i32
    float* lossacc = (float*)(wsb + 8192);  // 1 f32
    int* indices = (int*)(wsb + 16384);     // 32768 i32

    float* quant = out;             // [0, 8388608)
    float* scal = out + N_ELEM;     // loss @ +0, perplexity @ +1
    float* enc = out + N_ELEM + 2;  // [8388610, +33554432)

    // cbb (512KB, bf16 fragment order): in d_ws if it fits (fused path, enc
    // written by mega); else inside the enc region with a separate enc kernel
    // launched after mega completes (no concurrent read/write of that region).
    const bool fused = ws_size >= (size_t)(163840 + 524288);
    unsigned short* cbb = fused ? (unsigned short*)(wsb + 163840)
                                : (unsigned short*)(out + 8388612);

    hipLaunchKernelGGL(prep_kernel, dim3(128), dim3(256), 0, stream, cb, cbb,
                       cnorm, counts, lossacc);
    hipLaunchKernelGGL(mega_kernel, dim3(256), dim3(256), 0, stream, z, cbb, cb,
                       cnorm, indices, counts, lossacc, quant, enc, fused ? 1 : 0);
    if (!fused)
        hipLaunchKernelGGL(write_encodings, dim3(32768), dim3(256), 0, stream,
                           indices, enc);
    hipLaunchKernelGGL(finalize_kernel, dim3(1), dim3(256), 0, stream, counts,
                       lossacc, scal);
}